// Round 5
// baseline (263.792 us; speedup 1.0000x reference)
//
#include <hip/hip_runtime.h>

typedef unsigned short u16;
typedef __bf16 bf16x4 __attribute__((ext_vector_type(4)));
typedef __bf16 bf16x8 __attribute__((ext_vector_type(8)));
typedef float  f32x4  __attribute__((ext_vector_type(4)));
typedef float  f32x16 __attribute__((ext_vector_type(16)));

#define MFMA16(a, b, c) __builtin_amdgcn_mfma_f32_16x16x32_bf16((a), (b), (c), 0, 0, 0)
#define MFMA32(a, b, c) __builtin_amdgcn_mfma_f32_32x32x16_bf16((a), (b), (c), 0, 0, 0)

// ---------------------------------------------------------------------------
// Geometry: N=2, L=2048, E=1024, H=16, D=64.
// R4: barrier-free flash — K/V A-fragments read directly from global (per-head
// K,V = 256 KB each: L2-resident, L1-shared across the block's 4 waves), LDS
// kept only for the wave-private P round-trip -> zero __syncthreads in the
// K-sweep. Combine rewritten fully coalesced (LDS transpose).
// ---------------------------------------------------------------------------

// Kernel 1: Wo (1024x1024 f32) -> bf16
__global__ __launch_bounds__(256) void conv_wo_kernel(const float* __restrict__ Wo,
                                                      u16* __restrict__ Wob) {
    const int i = (blockIdx.x * 256 + threadIdx.x) * 4;
    float4 v = *(const float4*)&Wo[i];
    bf16x4 o = { (__bf16)v.x, (__bf16)v.y, (__bf16)v.z, (__bf16)v.w };
    *(bf16x4*)&Wob[i] = o;
}

// Kernel 2: shared projection  y = x @ Wv^T + bv  applied to values/keys/query.
// Q,K stored [nh][l][d] bf16; V stored transposed [nh][d][l] bf16.
// Q additionally scaled by c2 = log2(e)/sqrt(1024) (folded softmax scale).
__global__ __launch_bounds__(256) void proj_kernel(
    const float* __restrict__ values, const float* __restrict__ keys,
    const float* __restrict__ query,  const float* __restrict__ Wv,
    const float* __restrict__ bv,
    u16* __restrict__ Qb, u16* __restrict__ Kb, u16* __restrict__ VTb) {
    __shared__ __align__(16) u16 Wvs[64 * 72];
    __shared__ __align__(16) u16 Xs[64 * 72];
    const int b = blockIdx.x;
    const int lt = b & 31, h = (b >> 5) & 15, n = (b >> 9) & 1, t = b >> 10;
    const int nh = n * 16 + h, l0 = lt * 64;
    const int tid = threadIdx.x, wave = tid >> 6, lane = tid & 63;
    const int quad = lane >> 4, l16 = lane & 15;
    const float* xin = (t == 0) ? values : (t == 1 ? keys : query);

#pragma unroll
    for (int j = 0; j < 4; ++j) {
        const int chunk = tid + 256 * j, r = chunk >> 4, c = (chunk & 15) * 4;
        float4 w = *(const float4*)&Wv[r * 64 + c];
        bf16x4 wb = { (__bf16)w.x, (__bf16)w.y, (__bf16)w.z, (__bf16)w.w };
        *(bf16x4*)&Wvs[r * 72 + c] = wb;
        float4 x = *(const float4*)&xin[(size_t)(n * 2048 + l0 + r) * 1024 + h * 64 + c];
        bf16x4 xb = { (__bf16)x.x, (__bf16)x.y, (__bf16)x.z, (__bf16)x.w };
        *(bf16x4*)&Xs[r * 72 + c] = xb;
    }
    __syncthreads();

    bf16x8 wf[4][2], xf[2];
#pragma unroll
    for (int f = 0; f < 4; ++f)
#pragma unroll
        for (int ks = 0; ks < 2; ++ks)
            wf[f][ks] = *(const bf16x8*)&Wvs[(f * 16 + l16) * 72 + ks * 32 + quad * 8];
#pragma unroll
    for (int ks = 0; ks < 2; ++ks)
        xf[ks] = *(const bf16x8*)&Xs[(wave * 16 + l16) * 72 + ks * 32 + quad * 8];

    f32x4 acc[4];
#pragma unroll
    for (int i = 0; i < 4; ++i) acc[i] = (f32x4){0.f, 0.f, 0.f, 0.f};

    if (t == 0) {  // V: y = x·Wv^T
#pragma unroll
        for (int nf = 0; nf < 4; ++nf) {
            acc[nf] = MFMA16(xf[0], wf[nf][0], acc[nf]);
            acc[nf] = MFMA16(xf[1], wf[nf][1], acc[nf]);
        }
    } else {       // Q/K: y^T = Wv·x^T
#pragma unroll
        for (int mf = 0; mf < 4; ++mf) {
            acc[mf] = MFMA16(wf[mf][0], xf[0], acc[mf]);
            acc[mf] = MFMA16(wf[mf][1], xf[1], acc[mf]);
        }
    }
    __syncthreads();

    const float scale = (t == 2) ? 0.04508422f : 1.0f;  // log2(e)/sqrt(1024)
    if (t == 0) {
#pragma unroll
        for (int nf = 0; nf < 4; ++nf) {
            const float bias = bv[nf * 16 + l16];
            bf16x4 o = { (__bf16)(acc[nf][0] + bias), (__bf16)(acc[nf][1] + bias),
                         (__bf16)(acc[nf][2] + bias), (__bf16)(acc[nf][3] + bias) };
            *(bf16x4*)&Xs[(nf * 16 + l16) * 72 + wave * 16 + quad * 4] = o;
        }
    } else {
#pragma unroll
        for (int mf = 0; mf < 4; ++mf) {
            bf16x4 o = { (__bf16)((acc[mf][0] + bv[mf * 16 + quad * 4 + 0]) * scale),
                         (__bf16)((acc[mf][1] + bv[mf * 16 + quad * 4 + 1]) * scale),
                         (__bf16)((acc[mf][2] + bv[mf * 16 + quad * 4 + 2]) * scale),
                         (__bf16)((acc[mf][3] + bv[mf * 16 + quad * 4 + 3]) * scale) };
            *(bf16x4*)&Xs[(wave * 16 + l16) * 72 + mf * 16 + quad * 4] = o;
        }
    }
    __syncthreads();

    u16* dst = (t == 0) ? VTb : (t == 1 ? Kb : Qb);
#pragma unroll
    for (int j = 0; j < 2; ++j) {
        const int chunk = tid + 256 * j, r = chunk >> 3, c = (chunk & 7) * 8;
        const size_t off = (t == 0) ? (size_t)(nh * 64 + r) * 2048 + l0 + c
                                    : (size_t)(nh * 2048 + l0 + r) * 64 + c;
        *(int4*)&dst[off] = *(const int4*)&Xs[r * 72 + c];
    }
}

// Kernel 3: attention partials, 32x32x16 MFMA, split-K x2, BARRIER-FREE.
// Block = 256 thr (4 waves x 32 q); grid = 32 nh x 16 qslab x 2 ks.
// K/V fragments load directly from global (L1/L2-hot; all 4 waves share the
// same 8 KB/kt tiles). LDS only holds wave-private P (no __syncthreads).
// S^T = K·Q^T: C layout col=q=lane&31, row=key=(reg&3)+8*(reg>>2)+4*(lane>>5).
// O^T = V^T·P^T. Partial O (raw-reg order, coalesced b32) + partial l dumped.
__global__ __launch_bounds__(256, 4) void flash_kernel(
    const u16* __restrict__ Qb, const u16* __restrict__ Kb,
    const u16* __restrict__ VTb, float* __restrict__ Opart,
    float* __restrict__ Lp) {
    __shared__ __align__(16) u16 Ps[4][32 * 72];
    const int b = blockIdx.x;
    const int nh = b >> 5, ks = b & 1;
    const int tid = threadIdx.x, wave = tid >> 6, lane = tid & 63;
    const int l32 = lane & 31, half = lane >> 5;
    const int q0 = ((b >> 1) & 15) * 128 + wave * 32;
    const int s4 = (b >> 1) * 4 + wave;  // (nh*16+qsl)*4 + wave
    u16* Pw = &Ps[wave][0];

    // Q B-frags direct from global: B[kd=kg*16+half*8+j][q=l32].
    const u16* Qg = Qb + ((size_t)nh * 2048 + q0) * 64;
    bf16x8 qf[4];
#pragma unroll
    for (int kg = 0; kg < 4; ++kg)
        qf[kg] = *(const bf16x8*)&Qg[l32 * 64 + kg * 16 + half * 8];

    f32x16 Oacc[2];
#pragma unroll
    for (int dt = 0; dt < 2; ++dt)
#pragma unroll
        for (int r = 0; r < 16; ++r) Oacc[dt][r] = 0.f;
    float lsum = 0.f;

    const u16* Kg = Kb + (size_t)nh * 2048 * 64;
    const u16* Vg = VTb + (size_t)nh * 64 * 2048;

    for (int kt = 0; kt < 16; ++kt) {
        const int k0 = ks * 1024 + kt * 64;

        // Two 32-key S^T tiles; K A-frags straight from global.
#pragma unroll
        for (int t2 = 0; t2 < 2; ++t2) {
            f32x16 s;
#pragma unroll
            for (int r = 0; r < 16; ++r) s[r] = 0.f;
#pragma unroll
            for (int kg = 0; kg < 4; ++kg) {
                bf16x8 ak = *(const bf16x8*)&Kg[(size_t)(k0 + t2 * 32 + l32) * 64 + kg * 16 + half * 8];
                s = MFMA32(ak, qf[kg], s);
            }
            // exp, per-lane partial row sums, pack P^T[key][q] -> Pw[q][key].
            // reg r=4a+bb holds key = bb + 8a + 4*half (+32*t2), q = l32.
#pragma unroll
            for (int a = 0; a < 4; ++a) {
                const float p0 = __builtin_amdgcn_exp2f(s[4 * a + 0]);
                const float p1 = __builtin_amdgcn_exp2f(s[4 * a + 1]);
                const float p2 = __builtin_amdgcn_exp2f(s[4 * a + 2]);
                const float p3 = __builtin_amdgcn_exp2f(s[4 * a + 3]);
                lsum += (p0 + p1) + (p2 + p3);
                bf16x4 pk = { (__bf16)p0, (__bf16)p1, (__bf16)p2, (__bf16)p3 };
                *(bf16x4*)&Pw[l32 * 72 + t2 * 32 + a * 8 + half * 4] = pk;
            }
        }

        // O^T += V^T·P^T : A[m=d=dt*32+l32][k=key] direct from global VT.
#pragma unroll
        for (int kk = 0; kk < 4; ++kk) {
            bf16x8 bp = *(const bf16x8*)&Pw[l32 * 72 + kk * 16 + half * 8];
#pragma unroll
            for (int dt = 0; dt < 2; ++dt) {
                bf16x8 av = *(const bf16x8*)&Vg[(size_t)(dt * 32 + l32) * 2048 + k0 + kk * 16 + half * 8];
                Oacc[dt] = MFMA32(av, bp, Oacc[dt]);
            }
        }
    }

    // Dump partials: raw-reg order -> fully coalesced b32 stores.
    float* Ob = Opart + ((size_t)s4 * 2 + ks) * 2048;
#pragma unroll
    for (int dt = 0; dt < 2; ++dt)
#pragma unroll
        for (int r = 0; r < 16; ++r)
            Ob[(dt * 16 + r) * 64 + lane] = Oacc[dt][r];
    Lp[((size_t)s4 * 2 + ks) * 64 + lane] = lsum;  // per-(q,half) partial sum
}

// Kernel 3b: combine split-K partials -> AOb bf16 [4096][1024].
// Block = one s4 slab (32 q x 64 d). Coalesced float4 loads of both raw-layout
// ks slabs, add, LDS transpose (pitch 36 f32), normalized bf16x8 stores.
__global__ __launch_bounds__(256) void combine_kernel(
    const float* __restrict__ Opart, const float* __restrict__ Lp,
    u16* __restrict__ AOb) {
    __shared__ __align__(16) float Ls[64 * 36];
    const int s4 = blockIdx.x;
    const int nh = s4 >> 6, qsl = (s4 >> 2) & 15, w = s4 & 3;
    const int t = threadIdx.x;
    const size_t b0 = (size_t)s4 * 2 * 2048;

#pragma unroll
    for (int jj = 0; jj < 2; ++jj) {
        const int fi = t + jj * 256;            // float4 index 0..511
        float4 a = *(const float4*)&Opart[b0 + (size_t)fi * 4];
        float4 c = *(const float4*)&Opart[b0 + 2048 + (size_t)fi * 4];
        float4 sum = { a.x + c.x, a.y + c.y, a.z + c.z, a.w + c.w };
        const int flat = fi * 4, i = flat >> 6, lb = flat & 63;
        const int q = lb & 31, hf = lb >> 5, dtv = i >> 4, r = i & 15;
        const int d = (r & 3) + 8 * (r >> 2) + 4 * hf + 32 * dtv;
        *(float4*)&Ls[d * 36 + q] = sum;
    }
    __syncthreads();

    const int q = t >> 3, dg = t & 7;
    const float ls = Lp[(size_t)s4 * 2 * 64 + q] + Lp[(size_t)s4 * 2 * 64 + 32 + q]
                   + Lp[((size_t)s4 * 2 + 1) * 64 + q] + Lp[((size_t)s4 * 2 + 1) * 64 + 32 + q];
    const float inv = 1.0f / ls;

    bf16x8 o;
#pragma unroll
    for (int i = 0; i < 8; ++i)
        o[i] = (__bf16)(Ls[(dg * 8 + i) * 36 + q] * inv);
    const int row = (nh >> 4) * 2048 + qsl * 128 + w * 32 + q;
    const int col = (nh & 15) * 64 + dg * 8;
    *(bf16x8*)&AOb[(size_t)row * 1024 + col] = o;
}

// Kernel 4: out = AO(4096x1024 bf16) @ Wo^T + bo, f32 out.
// 64x64 block tile, grid 1024 -> 4 blocks/CU; wave w does rows w*16..+16.
__global__ __launch_bounds__(256) void out_gemm_kernel(
    const u16* __restrict__ A, const u16* __restrict__ Bw,
    const float* __restrict__ bo, float* __restrict__ out) {
    __shared__ __align__(16) u16 As[64 * 72];
    __shared__ __align__(16) u16 Bs[64 * 72];
    const int b = blockIdx.x, rt = b >> 4, ct = b & 15;
    const int row0 = rt * 64, col0 = ct * 64;
    const int tid = threadIdx.x, wave = tid >> 6, lane = tid & 63;
    const int quad = lane >> 4, l16 = lane & 15;

    f32x4 acc[4];
#pragma unroll
    for (int i = 0; i < 4; ++i) acc[i] = (f32x4){0.f, 0.f, 0.f, 0.f};

    for (int kt = 0; kt < 16; ++kt) {
        __syncthreads();
        const int k0 = kt * 64;
#pragma unroll
        for (int j = 0; j < 2; ++j) {
            const int chunk = tid + 256 * j, r = chunk >> 3, c = (chunk & 7) * 8;
            *(int4*)&As[r * 72 + c] = *(const int4*)&A[(size_t)(row0 + r) * 1024 + k0 + c];
            *(int4*)&Bs[r * 72 + c] = *(const int4*)&Bw[(size_t)(col0 + r) * 1024 + k0 + c];
        }
        __syncthreads();
#pragma unroll
        for (int ks = 0; ks < 2; ++ks) {
            bf16x8 af = *(const bf16x8*)&As[(wave * 16 + l16) * 72 + ks * 32 + quad * 8];
#pragma unroll
            for (int fc = 0; fc < 4; ++fc) {
                bf16x8 bfr = *(const bf16x8*)&Bs[(fc * 16 + l16) * 72 + ks * 32 + quad * 8];
                acc[fc] = MFMA16(af, bfr, acc[fc]);
            }
        }
    }

#pragma unroll
    for (int fc = 0; fc < 4; ++fc) {
        const float bias = bo[col0 + fc * 16 + l16];
        const int row = row0 + wave * 16 + quad * 4;
        const int col = col0 + fc * 16 + l16;
#pragma unroll
        for (int r = 0; r < 4; ++r)
            out[(size_t)(row + r) * 1024 + col] = acc[fc][r] + bias;
    }
}

extern "C" void kernel_launch(void* const* d_in, const int* in_sizes, int n_in,
                              void* d_out, int out_size, void* d_ws, size_t ws_size,
                              hipStream_t stream) {
    (void)in_sizes; (void)n_in; (void)out_size; (void)ws_size;
    const float* values = (const float*)d_in[0];
    const float* keys   = (const float*)d_in[1];
    const float* query  = (const float*)d_in[2];
    const float* Wv     = (const float*)d_in[3];
    const float* bv     = (const float*)d_in[4];
    const float* Wo     = (const float*)d_in[5];
    const float* bo     = (const float*)d_in[6];

    char* ws = (char*)d_ws;
    u16*   Qb    = (u16*)(ws);                     // [32][2048][64] bf16, 8 MB
    u16*   Kb    = (u16*)(ws + (8ull  << 20));     // [32][2048][64] bf16, 8 MB
    u16*   VTb   = (u16*)(ws + (16ull << 20));     // [32][64][2048] bf16, 8 MB
    u16*   AOb   = (u16*)(ws + (24ull << 20));     // [4096][1024]  bf16, 8 MB
    u16*   Wob   = (u16*)(ws + (32ull << 20));     // [1024][1024]  bf16, 2 MB
    float* Opart = (float*)(ws + (34ull << 20));   // [2048][2][2048] f32, 32 MB
    float* Lp    = (float*)(ws + (66ull << 20));   // [2048][2][64]  f32, 1 MB

    conv_wo_kernel<<<1024, 256, 0, stream>>>(Wo, Wob);
    proj_kernel<<<3072, 256, 0, stream>>>(values, keys, query, Wv, bv, Qb, Kb, VTb);
    flash_kernel<<<1024, 256, 0, stream>>>(Qb, Kb, VTb, Opart, Lp);
    combine_kernel<<<2048, 256, 0, stream>>>(Opart, Lp, AOb);
    out_gemm_kernel<<<1024, 256, 0, stream>>>(AOb, Wob, bo, (float*)d_out);
}

// Round 6
// 177.462 us; speedup vs baseline: 1.4865x; 1.4865x over previous
//
#include <hip/hip_runtime.h>

typedef unsigned short u16;
typedef __bf16 bf16x4 __attribute__((ext_vector_type(4)));
typedef __bf16 bf16x8 __attribute__((ext_vector_type(8)));
typedef float  f32x4  __attribute__((ext_vector_type(4)));
typedef float  f32x16 __attribute__((ext_vector_type(16)));

#define MFMA16(a, b, c) __builtin_amdgcn_mfma_f32_16x16x32_bf16((a), (b), (c), 0, 0, 0)
#define MFMA32(a, b, c) __builtin_amdgcn_mfma_f32_32x32x16_bf16((a), (b), (c), 0, 0, 0)

// ---------------------------------------------------------------------------
// Geometry: N=2, L=2048, E=1024, H=16, D=64.  LDS tiles: pitch 72 bf16.
// R5: flash reverted to R3 (staged LDS, split-K x2 — R4's direct-global frags
// were uncoalesced, 64 lines/instr, 2.7x regression). out_gemm rebuilt on
// MFMA32 with 128x64 tiles (halves LDS ops per output). conv_wo fused into
// proj (one fewer launch). combine stays R4-coalesced.
// ---------------------------------------------------------------------------

// Kernel 1: fused {Wo f32->bf16 convert | shared projection}.
// Blocks 0..3071: y = x @ Wv^T + bv for values/keys/query.
// Blocks 3072..4095: Wo convert.
// Q,K stored [nh][l][d] bf16; V stored transposed [nh][d][l] bf16.
// Q additionally scaled by log2(e)/sqrt(1024) (folded softmax scale).
__global__ __launch_bounds__(256) void prep_kernel(
    const float* __restrict__ values, const float* __restrict__ keys,
    const float* __restrict__ query,  const float* __restrict__ Wv,
    const float* __restrict__ bv,     const float* __restrict__ Wo,
    u16* __restrict__ Qb, u16* __restrict__ Kb, u16* __restrict__ VTb,
    u16* __restrict__ Wob) {
    const int b = blockIdx.x;
    const int t = b >> 10;
    if (t == 3) {  // Wo convert
        const int i = ((b - 3072) * 256 + threadIdx.x) * 4;
        float4 v = *(const float4*)&Wo[i];
        bf16x4 o = { (__bf16)v.x, (__bf16)v.y, (__bf16)v.z, (__bf16)v.w };
        *(bf16x4*)&Wob[i] = o;
        return;
    }
    __shared__ __align__(16) u16 Wvs[64 * 72];
    __shared__ __align__(16) u16 Xs[64 * 72];
    const int lt = b & 31, h = (b >> 5) & 15, n = (b >> 9) & 1;
    const int nh = n * 16 + h, l0 = lt * 64;
    const int tid = threadIdx.x, wave = tid >> 6, lane = tid & 63;
    const int quad = lane >> 4, l16 = lane & 15;
    const float* xin = (t == 0) ? values : (t == 1 ? keys : query);

#pragma unroll
    for (int j = 0; j < 4; ++j) {
        const int chunk = tid + 256 * j, r = chunk >> 4, c = (chunk & 15) * 4;
        float4 w = *(const float4*)&Wv[r * 64 + c];
        bf16x4 wb = { (__bf16)w.x, (__bf16)w.y, (__bf16)w.z, (__bf16)w.w };
        *(bf16x4*)&Wvs[r * 72 + c] = wb;
        float4 x = *(const float4*)&xin[(size_t)(n * 2048 + l0 + r) * 1024 + h * 64 + c];
        bf16x4 xb = { (__bf16)x.x, (__bf16)x.y, (__bf16)x.z, (__bf16)x.w };
        *(bf16x4*)&Xs[r * 72 + c] = xb;
    }
    __syncthreads();

    bf16x8 wf[4][2], xf[2];
#pragma unroll
    for (int f = 0; f < 4; ++f)
#pragma unroll
        for (int ks = 0; ks < 2; ++ks)
            wf[f][ks] = *(const bf16x8*)&Wvs[(f * 16 + l16) * 72 + ks * 32 + quad * 8];
#pragma unroll
    for (int ks = 0; ks < 2; ++ks)
        xf[ks] = *(const bf16x8*)&Xs[(wave * 16 + l16) * 72 + ks * 32 + quad * 8];

    f32x4 acc[4];
#pragma unroll
    for (int i = 0; i < 4; ++i) acc[i] = (f32x4){0.f, 0.f, 0.f, 0.f};

    if (t == 0) {  // V: y = x·Wv^T
#pragma unroll
        for (int nf = 0; nf < 4; ++nf) {
            acc[nf] = MFMA16(xf[0], wf[nf][0], acc[nf]);
            acc[nf] = MFMA16(xf[1], wf[nf][1], acc[nf]);
        }
    } else {       // Q/K: y^T = Wv·x^T
#pragma unroll
        for (int mf = 0; mf < 4; ++mf) {
            acc[mf] = MFMA16(wf[mf][0], xf[0], acc[mf]);
            acc[mf] = MFMA16(wf[mf][1], xf[1], acc[mf]);
        }
    }
    __syncthreads();

    const float scale = (t == 2) ? 0.04508422f : 1.0f;  // log2(e)/sqrt(1024)
    if (t == 0) {
#pragma unroll
        for (int nf = 0; nf < 4; ++nf) {
            const float bias = bv[nf * 16 + l16];
            bf16x4 o = { (__bf16)(acc[nf][0] + bias), (__bf16)(acc[nf][1] + bias),
                         (__bf16)(acc[nf][2] + bias), (__bf16)(acc[nf][3] + bias) };
            *(bf16x4*)&Xs[(nf * 16 + l16) * 72 + wave * 16 + quad * 4] = o;
        }
    } else {
#pragma unroll
        for (int mf = 0; mf < 4; ++mf) {
            bf16x4 o = { (__bf16)((acc[mf][0] + bv[mf * 16 + quad * 4 + 0]) * scale),
                         (__bf16)((acc[mf][1] + bv[mf * 16 + quad * 4 + 1]) * scale),
                         (__bf16)((acc[mf][2] + bv[mf * 16 + quad * 4 + 2]) * scale),
                         (__bf16)((acc[mf][3] + bv[mf * 16 + quad * 4 + 3]) * scale) };
            *(bf16x4*)&Xs[(wave * 16 + l16) * 72 + mf * 16 + quad * 4] = o;
        }
    }
    __syncthreads();

    u16* dst = (t == 0) ? VTb : (t == 1 ? Kb : Qb);
#pragma unroll
    for (int j = 0; j < 2; ++j) {
        const int chunk = tid + 256 * j, r = chunk >> 3, c = (chunk & 7) * 8;
        const size_t off = (t == 0) ? (size_t)(nh * 64 + r) * 2048 + l0 + c
                                    : (size_t)(nh * 2048 + l0 + r) * 64 + c;
        *(int4*)&dst[off] = *(const int4*)&Xs[r * 72 + c];
    }
}

// Kernel 2: attention partials with 32x32x16 MFMA + split-K x2 (R3 version).
// Block = 256 thr (4 waves x 32 q = 128-q slab); grid = 32 nh x 16 slab x 2 ks.
// S^T = K·Q^T per 32-key tile: C layout col=q=lane&31,
// row=key=(reg&3)+8*(reg>>2)+4*(lane>>5). exp -> P^T packed to wave-private
// LDS rows [q][key] (b64 writes, b128 frag reads, no barrier). O^T = V^T·P^T.
// Partial O (f32 raw-reg order) + partial l to workspace; combined later.
__global__ __launch_bounds__(256, 4) void flash_kernel(
    const u16* __restrict__ Qb, const u16* __restrict__ Kb,
    const u16* __restrict__ VTb, float* __restrict__ Opart,
    float* __restrict__ Lp) {
    __shared__ __align__(16) u16 Ks[64 * 72];
    __shared__ __align__(16) u16 Vs[64 * 72];
    __shared__ __align__(16) u16 Ps[4][32 * 72];
    const int b = blockIdx.x;
    const int nh = b >> 5, qsl = (b >> 1) & 15, ks = b & 1;
    const int tid = threadIdx.x, wave = tid >> 6, lane = tid & 63;
    const int l32 = lane & 31, half = lane >> 5;
    const int q0 = qsl * 128 + wave * 32;
    const int s4 = (b >> 1) * 4 + wave;  // (nh*16+qsl)*4 + wave
    u16* Pw = &Ps[wave][0];

    // Q B-frags direct from global: B[kd=kg*16+half*8+j][q=l32].
    const u16* Qg = Qb + ((size_t)nh * 2048 + q0) * 64;
    bf16x8 qf[4];
#pragma unroll
    for (int kg = 0; kg < 4; ++kg)
        qf[kg] = *(const bf16x8*)&Qg[l32 * 64 + kg * 16 + half * 8];

    f32x16 Oacc[2];
#pragma unroll
    for (int dt = 0; dt < 2; ++dt)
#pragma unroll
        for (int r = 0; r < 16; ++r) Oacc[dt][r] = 0.f;
    float lsum = 0.f;

    const u16* Kg = Kb + (size_t)nh * 2048 * 64;
    const u16* Vg = VTb + (size_t)nh * 64 * 2048;

    for (int kt = 0; kt < 16; ++kt) {
        __syncthreads();  // prior tile's Ks/Vs reads complete
        const int k0 = ks * 1024 + kt * 64;
#pragma unroll
        for (int j = 0; j < 2; ++j) {
            const int chunk = tid + 256 * j, r = chunk >> 3, c = (chunk & 7) * 8;
            *(int4*)&Ks[r * 72 + c] = *(const int4*)&Kg[(size_t)(k0 + r) * 64 + c];
            *(int4*)&Vs[r * 72 + c] = *(const int4*)&Vg[(size_t)r * 2048 + k0 + c];
        }
        __syncthreads();

        // Two 32-key S^T tiles: s = K(32xd64) · Q^T(d64 x 32q)
#pragma unroll
        for (int t2 = 0; t2 < 2; ++t2) {
            f32x16 s;
#pragma unroll
            for (int r = 0; r < 16; ++r) s[r] = 0.f;
#pragma unroll
            for (int kg = 0; kg < 4; ++kg) {
                bf16x8 ak = *(const bf16x8*)&Ks[(t2 * 32 + l32) * 72 + kg * 16 + half * 8];
                s = MFMA32(ak, qf[kg], s);
            }
            // exp, per-lane partial row sums, pack P^T[key][q] -> Pw[q][key].
            // reg r=4a+bb holds key = bb + 8a + 4*half (+32*t2), q = l32.
#pragma unroll
            for (int a = 0; a < 4; ++a) {
                const float p0 = __builtin_amdgcn_exp2f(s[4 * a + 0]);
                const float p1 = __builtin_amdgcn_exp2f(s[4 * a + 1]);
                const float p2 = __builtin_amdgcn_exp2f(s[4 * a + 2]);
                const float p3 = __builtin_amdgcn_exp2f(s[4 * a + 3]);
                lsum += (p0 + p1) + (p2 + p3);
                bf16x4 pk = { (__bf16)p0, (__bf16)p1, (__bf16)p2, (__bf16)p3 };
                *(bf16x4*)&Pw[l32 * 72 + t2 * 32 + a * 8 + half * 4] = pk;
            }
        }

        // O^T += V^T·P^T : A[m=d=dt*32+l32][k=key], B[k=key][q=l32]
#pragma unroll
        for (int kk = 0; kk < 4; ++kk) {
            bf16x8 bp = *(const bf16x8*)&Pw[l32 * 72 + kk * 16 + half * 8];
#pragma unroll
            for (int dt = 0; dt < 2; ++dt) {
                bf16x8 av = *(const bf16x8*)&Vs[(dt * 32 + l32) * 72 + kk * 16 + half * 8];
                Oacc[dt] = MFMA32(av, bp, Oacc[dt]);
            }
        }
    }

    // Dump partials: raw-reg order -> fully coalesced b32 stores.
    float* Ob = Opart + ((size_t)s4 * 2 + ks) * 2048;
#pragma unroll
    for (int dt = 0; dt < 2; ++dt)
#pragma unroll
        for (int r = 0; r < 16; ++r)
            Ob[(dt * 16 + r) * 64 + lane] = Oacc[dt][r];
    Lp[((size_t)s4 * 2 + ks) * 64 + lane] = lsum;  // per-(q,half) partial sum
}

// Kernel 3: combine split-K partials -> AOb bf16 [4096][1024].
// Block = one s4 slab (32 q x 64 d). Coalesced float4 loads of both raw-layout
// ks slabs, add, LDS transpose (pitch 36 f32), normalized bf16x8 stores.
__global__ __launch_bounds__(256) void combine_kernel(
    const float* __restrict__ Opart, const float* __restrict__ Lp,
    u16* __restrict__ AOb) {
    __shared__ __align__(16) float Ls[64 * 36];
    const int s4 = blockIdx.x;
    const int nh = s4 >> 6, qsl = (s4 >> 2) & 15, w = s4 & 3;
    const int t = threadIdx.x;
    const size_t b0 = (size_t)s4 * 2 * 2048;

#pragma unroll
    for (int jj = 0; jj < 2; ++jj) {
        const int fi = t + jj * 256;            // float4 index 0..511
        float4 a = *(const float4*)&Opart[b0 + (size_t)fi * 4];
        float4 c = *(const float4*)&Opart[b0 + 2048 + (size_t)fi * 4];
        float4 sum = { a.x + c.x, a.y + c.y, a.z + c.z, a.w + c.w };
        const int flat = fi * 4, i = flat >> 6, lb = flat & 63;
        const int q = lb & 31, hf = lb >> 5, dtv = i >> 4, r = i & 15;
        const int d = (r & 3) + 8 * (r >> 2) + 4 * hf + 32 * dtv;
        *(float4*)&Ls[d * 36 + q] = sum;
    }
    __syncthreads();

    const int q = t >> 3, dg = t & 7;
    const float ls = Lp[(size_t)s4 * 2 * 64 + q] + Lp[(size_t)s4 * 2 * 64 + 32 + q]
                   + Lp[((size_t)s4 * 2 + 1) * 64 + q] + Lp[((size_t)s4 * 2 + 1) * 64 + 32 + q];
    const float inv = 1.0f / ls;

    bf16x8 o;
#pragma unroll
    for (int i = 0; i < 8; ++i)
        o[i] = (__bf16)(Ls[(dg * 8 + i) * 36 + q] * inv);
    const int row = (nh >> 4) * 2048 + qsl * 128 + w * 32 + q;
    const int col = (nh & 15) * 64 + dg * 8;
    *(bf16x8*)&AOb[(size_t)row * 1024 + col] = o;
}

// Kernel 4: out = AO(4096x1024 bf16) @ Wo^T + bo, f32 out.
// R5: MFMA32, 128x64 block tile, grid 512 (32 rt x 16 ct) -> 2 blocks/CU.
// Wave w owns rows w*32..+32; cg loop over two 32-col groups.
__global__ __launch_bounds__(256) void out_gemm_kernel(
    const u16* __restrict__ A, const u16* __restrict__ Bw,
    const float* __restrict__ bo, float* __restrict__ out) {
    __shared__ __align__(16) u16 As[128 * 72];
    __shared__ __align__(16) u16 Bs[64 * 72];
    const int b = blockIdx.x, rt = b >> 4, ct = b & 15;
    const int row0 = rt * 128, col0 = ct * 64;
    const int tid = threadIdx.x, wave = tid >> 6, lane = tid & 63;
    const int l32 = lane & 31, half = lane >> 5;

    f32x16 acc[2];
#pragma unroll
    for (int cg = 0; cg < 2; ++cg)
#pragma unroll
        for (int r = 0; r < 16; ++r) acc[cg][r] = 0.f;

    for (int kt = 0; kt < 16; ++kt) {
        __syncthreads();
        const int k0 = kt * 64;
#pragma unroll
        for (int j = 0; j < 4; ++j) {
            const int chunk = tid + 256 * j, r = chunk >> 3, c = (chunk & 7) * 8;
            *(int4*)&As[r * 72 + c] = *(const int4*)&A[(size_t)(row0 + r) * 1024 + k0 + c];
        }
#pragma unroll
        for (int j = 0; j < 2; ++j) {
            const int chunk = tid + 256 * j, r = chunk >> 3, c = (chunk & 7) * 8;
            *(int4*)&Bs[r * 72 + c] = *(const int4*)&Bw[(size_t)(col0 + r) * 1024 + k0 + c];
        }
        __syncthreads();
#pragma unroll
        for (int kg = 0; kg < 4; ++kg) {
            bf16x8 af = *(const bf16x8*)&As[(wave * 32 + l32) * 72 + kg * 16 + half * 8];
#pragma unroll
            for (int cg = 0; cg < 2; ++cg) {
                bf16x8 bf = *(const bf16x8*)&Bs[(cg * 32 + l32) * 72 + kg * 16 + half * 8];
                acc[cg] = MFMA32(af, bf, acc[cg]);
            }
        }
    }

    // C layout: col = l32 (local), row = (r&3)+8*(r>>2)+4*half (local).
#pragma unroll
    for (int cg = 0; cg < 2; ++cg) {
        const int col = col0 + cg * 32 + l32;
        const float bias = bo[col];
#pragma unroll
        for (int r = 0; r < 16; ++r) {
            const int row = row0 + wave * 32 + (r & 3) + 8 * (r >> 2) + 4 * half;
            out[(size_t)row * 1024 + col] = acc[cg][r] + bias;
        }
    }
}

extern "C" void kernel_launch(void* const* d_in, const int* in_sizes, int n_in,
                              void* d_out, int out_size, void* d_ws, size_t ws_size,
                              hipStream_t stream) {
    (void)in_sizes; (void)n_in; (void)out_size; (void)ws_size;
    const float* values = (const float*)d_in[0];
    const float* keys   = (const float*)d_in[1];
    const float* query  = (const float*)d_in[2];
    const float* Wv     = (const float*)d_in[3];
    const float* bv     = (const float*)d_in[4];
    const float* Wo     = (const float*)d_in[5];
    const float* bo     = (const float*)d_in[6];

    char* ws = (char*)d_ws;
    u16*   Qb    = (u16*)(ws);                     // [32][2048][64] bf16, 8 MB
    u16*   Kb    = (u16*)(ws + (8ull  << 20));     // [32][2048][64] bf16, 8 MB
    u16*   VTb   = (u16*)(ws + (16ull << 20));     // [32][64][2048] bf16, 8 MB
    u16*   AOb   = (u16*)(ws + (24ull << 20));     // [4096][1024]  bf16, 8 MB
    u16*   Wob   = (u16*)(ws + (32ull << 20));     // [1024][1024]  bf16, 2 MB
    float* Opart = (float*)(ws + (34ull << 20));   // [2048][2][2048] f32, 32 MB
    float* Lp    = (float*)(ws + (66ull << 20));   // [2048][2][64]  f32, 1 MB

    prep_kernel<<<4096, 256, 0, stream>>>(values, keys, query, Wv, bv, Wo,
                                          Qb, Kb, VTb, Wob);
    flash_kernel<<<1024, 256, 0, stream>>>(Qb, Kb, VTb, Opart, Lp);
    combine_kernel<<<2048, 256, 0, stream>>>(Opart, Lp, AOb);
    out_gemm_kernel<<<512, 256, 0, stream>>>(AOb, Wob, bo, (float*)d_out);
}

// Round 7
// 166.929 us; speedup vs baseline: 1.5803x; 1.0631x over previous
//
#include <hip/hip_runtime.h>

typedef unsigned short u16;
typedef __bf16 bf16x4 __attribute__((ext_vector_type(4)));
typedef __bf16 bf16x8 __attribute__((ext_vector_type(8)));
typedef float  f32x4  __attribute__((ext_vector_type(4)));
typedef float  f32x16 __attribute__((ext_vector_type(16)));

#define MFMA16(a, b, c) __builtin_amdgcn_mfma_f32_16x16x32_bf16((a), (b), (c), 0, 0, 0)
#define MFMA32(a, b, c) __builtin_amdgcn_mfma_f32_32x32x16_bf16((a), (b), (c), 0, 0, 0)

// ---------------------------------------------------------------------------
// Geometry: N=2, L=2048, E=1024, H=16, D=64.  LDS tiles: pitch 72 bf16.
// R7: flash K-loop unchanged (proven 48 us); epilogue now transposes O^T->O
// in-wave and stores bf16 partials in final AO layout + folded per-q l.
// Combine is pure elementwise (O1+O2)*inv_l. out_gemm 512-thr (16 waves/CU).
// ws shrunk 67->51 MB.
// ---------------------------------------------------------------------------

// Kernel 1: fused {Wo f32->bf16 convert | shared projection}.
// Blocks 0..3071: y = x @ Wv^T + bv for values/keys/query.
// Blocks 3072..4095: Wo convert.
// Q,K stored [nh][l][d] bf16; V stored transposed [nh][d][l] bf16.
// Q additionally scaled by log2(e)/sqrt(1024) (folded softmax scale).
__global__ __launch_bounds__(256) void prep_kernel(
    const float* __restrict__ values, const float* __restrict__ keys,
    const float* __restrict__ query,  const float* __restrict__ Wv,
    const float* __restrict__ bv,     const float* __restrict__ Wo,
    u16* __restrict__ Qb, u16* __restrict__ Kb, u16* __restrict__ VTb,
    u16* __restrict__ Wob) {
    const int b = blockIdx.x;
    const int t = b >> 10;
    if (t == 3) {  // Wo convert
        const int i = ((b - 3072) * 256 + threadIdx.x) * 4;
        float4 v = *(const float4*)&Wo[i];
        bf16x4 o = { (__bf16)v.x, (__bf16)v.y, (__bf16)v.z, (__bf16)v.w };
        *(bf16x4*)&Wob[i] = o;
        return;
    }
    __shared__ __align__(16) u16 Wvs[64 * 72];
    __shared__ __align__(16) u16 Xs[64 * 72];
    const int lt = b & 31, h = (b >> 5) & 15, n = (b >> 9) & 1;
    const int nh = n * 16 + h, l0 = lt * 64;
    const int tid = threadIdx.x, wave = tid >> 6, lane = tid & 63;
    const int quad = lane >> 4, l16 = lane & 15;
    const float* xin = (t == 0) ? values : (t == 1 ? keys : query);

#pragma unroll
    for (int j = 0; j < 4; ++j) {
        const int chunk = tid + 256 * j, r = chunk >> 4, c = (chunk & 15) * 4;
        float4 w = *(const float4*)&Wv[r * 64 + c];
        bf16x4 wb = { (__bf16)w.x, (__bf16)w.y, (__bf16)w.z, (__bf16)w.w };
        *(bf16x4*)&Wvs[r * 72 + c] = wb;
        float4 x = *(const float4*)&xin[(size_t)(n * 2048 + l0 + r) * 1024 + h * 64 + c];
        bf16x4 xb = { (__bf16)x.x, (__bf16)x.y, (__bf16)x.z, (__bf16)x.w };
        *(bf16x4*)&Xs[r * 72 + c] = xb;
    }
    __syncthreads();

    bf16x8 wf[4][2], xf[2];
#pragma unroll
    for (int f = 0; f < 4; ++f)
#pragma unroll
        for (int ks = 0; ks < 2; ++ks)
            wf[f][ks] = *(const bf16x8*)&Wvs[(f * 16 + l16) * 72 + ks * 32 + quad * 8];
#pragma unroll
    for (int ks = 0; ks < 2; ++ks)
        xf[ks] = *(const bf16x8*)&Xs[(wave * 16 + l16) * 72 + ks * 32 + quad * 8];

    f32x4 acc[4];
#pragma unroll
    for (int i = 0; i < 4; ++i) acc[i] = (f32x4){0.f, 0.f, 0.f, 0.f};

    if (t == 0) {  // V: y = x·Wv^T
#pragma unroll
        for (int nf = 0; nf < 4; ++nf) {
            acc[nf] = MFMA16(xf[0], wf[nf][0], acc[nf]);
            acc[nf] = MFMA16(xf[1], wf[nf][1], acc[nf]);
        }
    } else {       // Q/K: y^T = Wv·x^T
#pragma unroll
        for (int mf = 0; mf < 4; ++mf) {
            acc[mf] = MFMA16(wf[mf][0], xf[0], acc[mf]);
            acc[mf] = MFMA16(wf[mf][1], xf[1], acc[mf]);
        }
    }
    __syncthreads();

    const float scale = (t == 2) ? 0.04508422f : 1.0f;  // log2(e)/sqrt(1024)
    if (t == 0) {
#pragma unroll
        for (int nf = 0; nf < 4; ++nf) {
            const float bias = bv[nf * 16 + l16];
            bf16x4 o = { (__bf16)(acc[nf][0] + bias), (__bf16)(acc[nf][1] + bias),
                         (__bf16)(acc[nf][2] + bias), (__bf16)(acc[nf][3] + bias) };
            *(bf16x4*)&Xs[(nf * 16 + l16) * 72 + wave * 16 + quad * 4] = o;
        }
    } else {
#pragma unroll
        for (int mf = 0; mf < 4; ++mf) {
            bf16x4 o = { (__bf16)((acc[mf][0] + bv[mf * 16 + quad * 4 + 0]) * scale),
                         (__bf16)((acc[mf][1] + bv[mf * 16 + quad * 4 + 1]) * scale),
                         (__bf16)((acc[mf][2] + bv[mf * 16 + quad * 4 + 2]) * scale),
                         (__bf16)((acc[mf][3] + bv[mf * 16 + quad * 4 + 3]) * scale) };
            *(bf16x4*)&Xs[(wave * 16 + l16) * 72 + mf * 16 + quad * 4] = o;
        }
    }
    __syncthreads();

    u16* dst = (t == 0) ? VTb : (t == 1 ? Kb : Qb);
#pragma unroll
    for (int j = 0; j < 2; ++j) {
        const int chunk = tid + 256 * j, r = chunk >> 3, c = (chunk & 7) * 8;
        const size_t off = (t == 0) ? (size_t)(nh * 64 + r) * 2048 + l0 + c
                                    : (size_t)(nh * 2048 + l0 + r) * 64 + c;
        *(int4*)&dst[off] = *(const int4*)&Xs[r * 72 + c];
    }
}

// Kernel 2: attention partials with 32x32x16 MFMA + split-K x2.
// Block = 256 thr (4 waves x 32 q = 128-q slab); grid = 32 nh x 16 slab x 2 ks.
// K-loop identical to R5/R6 (measured 48 us). Epilogue: fold per-q l via
// shfl_xor(32); transpose O^T->O through the wave-private P region; store
// UNNORMALIZED bf16 partials directly in AO layout (Op[ks] = [4096][1024]).
__global__ __launch_bounds__(256, 4) void flash_kernel(
    const u16* __restrict__ Qb, const u16* __restrict__ Kb,
    const u16* __restrict__ VTb, u16* __restrict__ Op,
    float* __restrict__ Lp) {
    __shared__ __align__(16) u16 Ks[64 * 72];
    __shared__ __align__(16) u16 Vs[64 * 72];
    __shared__ __align__(16) u16 Ps[4][32 * 72];
    const int b = blockIdx.x;
    const int nh = b >> 5, qsl = (b >> 1) & 15, ks = b & 1;
    const int tid = threadIdx.x, wave = tid >> 6, lane = tid & 63;
    const int l32 = lane & 31, half = lane >> 5;
    const int q0 = qsl * 128 + wave * 32;
    const int s4 = (b >> 1) * 4 + wave;  // (nh*16+qsl)*4 + wave
    u16* Pw = &Ps[wave][0];

    // Q B-frags direct from global: B[kd=kg*16+half*8+j][q=l32].
    const u16* Qg = Qb + ((size_t)nh * 2048 + q0) * 64;
    bf16x8 qf[4];
#pragma unroll
    for (int kg = 0; kg < 4; ++kg)
        qf[kg] = *(const bf16x8*)&Qg[l32 * 64 + kg * 16 + half * 8];

    f32x16 Oacc[2];
#pragma unroll
    for (int dt = 0; dt < 2; ++dt)
#pragma unroll
        for (int r = 0; r < 16; ++r) Oacc[dt][r] = 0.f;
    float lsum = 0.f;

    const u16* Kg = Kb + (size_t)nh * 2048 * 64;
    const u16* Vg = VTb + (size_t)nh * 64 * 2048;

    for (int kt = 0; kt < 16; ++kt) {
        __syncthreads();  // prior tile's Ks/Vs reads complete
        const int k0 = ks * 1024 + kt * 64;
#pragma unroll
        for (int j = 0; j < 2; ++j) {
            const int chunk = tid + 256 * j, r = chunk >> 3, c = (chunk & 7) * 8;
            *(int4*)&Ks[r * 72 + c] = *(const int4*)&Kg[(size_t)(k0 + r) * 64 + c];
            *(int4*)&Vs[r * 72 + c] = *(const int4*)&Vg[(size_t)r * 2048 + k0 + c];
        }
        __syncthreads();

        // Two 32-key S^T tiles: s = K(32xd64) · Q^T(d64 x 32q)
#pragma unroll
        for (int t2 = 0; t2 < 2; ++t2) {
            f32x16 s;
#pragma unroll
            for (int r = 0; r < 16; ++r) s[r] = 0.f;
#pragma unroll
            for (int kg = 0; kg < 4; ++kg) {
                bf16x8 ak = *(const bf16x8*)&Ks[(t2 * 32 + l32) * 72 + kg * 16 + half * 8];
                s = MFMA32(ak, qf[kg], s);
            }
            // exp, per-lane partial row sums, pack P^T[key][q] -> Pw[q][key].
            // reg r=4a+bb holds key = bb + 8a + 4*half (+32*t2), q = l32.
#pragma unroll
            for (int a = 0; a < 4; ++a) {
                const float p0 = __builtin_amdgcn_exp2f(s[4 * a + 0]);
                const float p1 = __builtin_amdgcn_exp2f(s[4 * a + 1]);
                const float p2 = __builtin_amdgcn_exp2f(s[4 * a + 2]);
                const float p3 = __builtin_amdgcn_exp2f(s[4 * a + 3]);
                lsum += (p0 + p1) + (p2 + p3);
                bf16x4 pk = { (__bf16)p0, (__bf16)p1, (__bf16)p2, (__bf16)p3 };
                *(bf16x4*)&Pw[l32 * 72 + t2 * 32 + a * 8 + half * 4] = pk;
            }
        }

        // O^T += V^T·P^T : A[m=d=dt*32+l32][k=key], B[k=key][q=l32]
#pragma unroll
        for (int kk = 0; kk < 4; ++kk) {
            bf16x8 bp = *(const bf16x8*)&Pw[l32 * 72 + kk * 16 + half * 8];
#pragma unroll
            for (int dt = 0; dt < 2; ++dt) {
                bf16x8 av = *(const bf16x8*)&Vs[(dt * 32 + l32) * 72 + kk * 16 + half * 8];
                Oacc[dt] = MFMA32(av, bp, Oacc[dt]);
            }
        }
    }

    // Fold the two key-halves of this lane's partial row sum -> l(q) per ks.
    const float lq = lsum + __shfl_xor(lsum, 32);
    if (half == 0)
        Lp[((size_t)s4 * 2 + ks) * 32 + l32] = lq;

    // Transpose O^T (C layout: col=q=l32, row=d=(r&3)+8*(r>>2)+4*half+32*dt)
    // into O[q][d] via the wave-private P region, then store bf16 partials
    // in final AO layout (coalesced b128).
#pragma unroll
    for (int dt = 0; dt < 2; ++dt)
#pragma unroll
        for (int a = 0; a < 4; ++a) {
            bf16x4 o = { (__bf16)Oacc[dt][4 * a + 0], (__bf16)Oacc[dt][4 * a + 1],
                         (__bf16)Oacc[dt][4 * a + 2], (__bf16)Oacc[dt][4 * a + 3] };
            *(bf16x4*)&Pw[l32 * 72 + dt * 32 + a * 8 + half * 4] = o;
        }
    u16* Ob = Op + (size_t)ks * 4194304 +
              ((size_t)(nh >> 4) * 2048 + q0) * 1024 + (nh & 15) * 64;
#pragma unroll
    for (int j = 0; j < 4; ++j) {
        const int chunk = lane + 64 * j, r = chunk >> 3, c = (chunk & 7) * 8;
        *(int4*)&Ob[(size_t)r * 1024 + c] = *(const int4*)&Pw[r * 72 + c];
    }
}

// Kernel 3: elementwise combine: AO = (O1 + O2) * inv_l, all bf16 in AO layout.
// Thread -> one bf16x8 unit. u = b*256+t: row = u>>7, ecol = (u&127)*8.
__global__ __launch_bounds__(256) void combine_kernel(
    const u16* __restrict__ Op, const float* __restrict__ Lp,
    u16* __restrict__ AOb) {
    const int u = blockIdx.x * 256 + threadIdx.x;
    const int row = u >> 7, ecol = (u & 127) * 8;
    const int h = ecol >> 6;
    const int n = row >> 11, qsl = (row >> 7) & 15, w = (row >> 5) & 3, q = row & 31;
    const int s4 = (((n * 16 + h) * 16 + qsl) << 2) + w;
    const float l = Lp[(size_t)s4 * 2 * 32 + q] + Lp[((size_t)s4 * 2 + 1) * 32 + q];
    const float inv = 1.0f / l;
    const size_t off = (size_t)row * 1024 + ecol;
    bf16x8 a = *(const bf16x8*)&Op[off];
    bf16x8 c = *(const bf16x8*)&Op[4194304 + off];
    bf16x8 o;
#pragma unroll
    for (int i = 0; i < 8; ++i)
        o[i] = (__bf16)(((float)a[i] + (float)c[i]) * inv);
    *(bf16x8*)&AOb[off] = o;
}

// Kernel 4: out = AO(4096x1024 bf16) @ Wo^T + bo, f32 out.
// R7: 512-thr blocks, 128x64 tile, 8 waves each one 32x32 subtile (MFMA32).
// Grid 512 -> 2 blocks/CU = 16 waves/CU.
__global__ __launch_bounds__(512) void out_gemm_kernel(
    const u16* __restrict__ A, const u16* __restrict__ Bw,
    const float* __restrict__ bo, float* __restrict__ out) {
    __shared__ __align__(16) u16 As[128 * 72];
    __shared__ __align__(16) u16 Bs[64 * 72];
    const int b = blockIdx.x, rt = b >> 4, ct = b & 15;
    const int row0 = rt * 128, col0 = ct * 64;
    const int tid = threadIdx.x, wave = tid >> 6, lane = tid & 63;
    const int l32 = lane & 31, half = lane >> 5;
    const int wr = wave & 3, wc = wave >> 2;

    f32x16 acc;
#pragma unroll
    for (int r = 0; r < 16; ++r) acc[r] = 0.f;

    for (int kt = 0; kt < 16; ++kt) {
        __syncthreads();
        const int k0 = kt * 64;
#pragma unroll
        for (int j = 0; j < 2; ++j) {
            const int chunk = tid + 512 * j, r = chunk >> 3, c = (chunk & 7) * 8;
            *(int4*)&As[r * 72 + c] = *(const int4*)&A[(size_t)(row0 + r) * 1024 + k0 + c];
        }
        {
            const int r = tid >> 3, c = (tid & 7) * 8;
            *(int4*)&Bs[r * 72 + c] = *(const int4*)&Bw[(size_t)(col0 + r) * 1024 + k0 + c];
        }
        __syncthreads();
#pragma unroll
        for (int kg = 0; kg < 4; ++kg) {
            bf16x8 af = *(const bf16x8*)&As[(wr * 32 + l32) * 72 + kg * 16 + half * 8];
            bf16x8 bf = *(const bf16x8*)&Bs[(wc * 32 + l32) * 72 + kg * 16 + half * 8];
            acc = MFMA32(af, bf, acc);
        }
    }

    // C layout: col = l32 (local), row = (r&3)+8*(r>>2)+4*half (local).
    const int col = col0 + wc * 32 + l32;
    const float bias = bo[col];
#pragma unroll
    for (int r = 0; r < 16; ++r) {
        const int row = row0 + wr * 32 + (r & 3) + 8 * (r >> 2) + 4 * half;
        out[(size_t)row * 1024 + col] = acc[r] + bias;
    }
}

extern "C" void kernel_launch(void* const* d_in, const int* in_sizes, int n_in,
                              void* d_out, int out_size, void* d_ws, size_t ws_size,
                              hipStream_t stream) {
    (void)in_sizes; (void)n_in; (void)out_size; (void)ws_size;
    const float* values = (const float*)d_in[0];
    const float* keys   = (const float*)d_in[1];
    const float* query  = (const float*)d_in[2];
    const float* Wv     = (const float*)d_in[3];
    const float* bv     = (const float*)d_in[4];
    const float* Wo     = (const float*)d_in[5];
    const float* bo     = (const float*)d_in[6];

    char* ws = (char*)d_ws;
    u16*   Qb  = (u16*)(ws);                     // [32][2048][64] bf16, 8 MB
    u16*   Kb  = (u16*)(ws + (8ull  << 20));     // [32][2048][64] bf16, 8 MB
    u16*   VTb = (u16*)(ws + (16ull << 20));     // [32][64][2048] bf16, 8 MB
    u16*   AOb = (u16*)(ws + (24ull << 20));     // [4096][1024]  bf16, 8 MB
    u16*   Wob = (u16*)(ws + (32ull << 20));     // [1024][1024]  bf16, 2 MB
    u16*   Op  = (u16*)(ws + (34ull << 20));     // 2 x [4096][1024] bf16, 16 MB
    float* Lp  = (float*)(ws + (50ull << 20));   // [2048][2][32] f32, 512 KB

    prep_kernel<<<4096, 256, 0, stream>>>(values, keys, query, Wv, bv, Wo,
                                          Qb, Kb, VTb, Wob);
    flash_kernel<<<1024, 256, 0, stream>>>(Qb, Kb, VTb, Op, Lp);
    combine_kernel<<<2048, 256, 0, stream>>>(Op, Lp, AOb);
    out_gemm_kernel<<<512, 512, 0, stream>>>(AOb, Wob, bo, (float*)d_out);
}